// Round 1
// baseline (2074.593 us; speedup 1.0000x reference)
//
#include <hip/hip_runtime.h>

#define DIM 64

// row_ptr[r] = lower_bound(rows, r): first index i with rows[i] >= r.
// rows is sorted, so segment for row r = [row_ptr[r], row_ptr[r+1]).
__global__ void build_row_ptr_kernel(const int* __restrict__ rows, int nnz,
                                     int n, int* __restrict__ row_ptr) {
    int r = blockIdx.x * blockDim.x + threadIdx.x;
    if (r > n) return;
    int lo = 0, hi = nnz;
    while (lo < hi) {
        int mid = (lo + hi) >> 1;
        if (rows[mid] < r) lo = mid + 1; else hi = mid;
    }
    row_ptr[r] = lo;
}

// One wave (64 lanes) per output row; lane = dim.
// e1 = A1 @ x0 ; acc = x0 + e1   (start of the 5-embedding mean)
__global__ __launch_bounds__(256) void spmm_first_kernel(
    const float* __restrict__ x0, const float* __restrict__ vals,
    const int* __restrict__ cols, const int* __restrict__ row_ptr,
    int n, float* __restrict__ e1, float* __restrict__ acc)
{
    int row  = (int)((blockIdx.x * (unsigned)blockDim.x + threadIdx.x) >> 6);
    int lane = threadIdx.x & 63;
    if (row >= n) return;
    int start = row_ptr[row], end = row_ptr[row + 1];
    float s = 0.f;
    for (int j = start; j < end; ++j) {
        int   c = cols[j];
        float v = vals[j];
        s += v * x0[(size_t)c * DIM + lane];
    }
    size_t o = (size_t)row * DIM + lane;
    e1[o]  = s;
    acc[o] = x0[o] + s;
}

// One layer: prop = A2 @ eprev; b = pearson(eprev_row, x0_row);
// enew = b*prop + (1-b)*x0; acc += enew (final: acc = (acc+enew)/5).
template <bool FINAL>
__global__ __launch_bounds__(256) void layer_kernel(
    const float* __restrict__ x0, const float* __restrict__ eprev,
    const float* __restrict__ vals2, const int* __restrict__ cols2,
    const int* __restrict__ row_ptr2, int n,
    float* __restrict__ enew, float* __restrict__ acc)
{
    int row  = (int)((blockIdx.x * (unsigned)blockDim.x + threadIdx.x) >> 6);
    int lane = threadIdx.x & 63;
    if (row >= n) return;
    int start = row_ptr2[row], end = row_ptr2[row + 1];
    float prop = 0.f;
    for (int j = start; j < end; ++j) {
        int   c = cols2[j];
        float v = vals2[j];
        prop += v * eprev[(size_t)c * DIM + lane];
    }
    size_t o  = (size_t)row * DIM + lane;
    float xp = eprev[o];
    float y0 = x0[o];

    // Wave-64 reductions for Pearson over the 64 dims.
    float sx = xp, sy = y0;
    #pragma unroll
    for (int m = 1; m < 64; m <<= 1) {
        sx += __shfl_xor(sx, m);
        sy += __shfl_xor(sy, m);
    }
    float mx = sx * (1.f / 64.f), my = sy * (1.f / 64.f);
    float xd = xp - mx, yd = y0 - my;
    float sxy = xd * yd, sxx = xd * xd, syy = yd * yd;
    #pragma unroll
    for (int m = 1; m < 64; m <<= 1) {
        sxy += __shfl_xor(sxy, m);
        sxx += __shfl_xor(sxx, m);
        syy += __shfl_xor(syy, m);
    }
    float den = sqrtf(sxx) * sqrtf(syy);
    den = (den < 1e-7f) ? 1e-7f : den;
    float b  = sxy / den;
    float en = b * prop + (1.f - b) * y0;

    if (!FINAL) {
        enew[o] = en;
        acc[o] += en;
    } else {
        acc[o] = (acc[o] + en) * 0.2f;  // mean of 5 embeddings
    }
}

extern "C" void kernel_launch(void* const* d_in, const int* in_sizes, int n_in,
                              void* d_out, int out_size, void* d_ws, size_t ws_size,
                              hipStream_t stream) {
    const float* emb   = (const float*)d_in[0];
    const float* vals  = (const float*)d_in[1];
    const float* vals2 = (const float*)d_in[2];
    const int*   rows  = (const int*)d_in[3];
    const int*   cols  = (const int*)d_in[4];
    const int*   rows2 = (const int*)d_in[5];
    const int*   cols2 = (const int*)d_in[6];
    // n_layers = 3 (fixed Python scalar; device-resident, unreadable under capture)

    const int n    = in_sizes[0] / DIM;   // 300000
    const int nnz  = in_sizes[1];         // 4800000
    const int nnz2 = in_sizes[2];

    float* out = (float*)d_out;           // doubles as the mean accumulator

    // Workspace layout: rp1 | rp2 | bufA | bufB
    char*  ws       = (char*)d_ws;
    size_t rp_bytes = (((size_t)(n + 1) * sizeof(int)) + 255) & ~(size_t)255;
    int*   rp1  = (int*)ws;
    int*   rp2  = (int*)(ws + rp_bytes);
    float* bufA = (float*)(ws + 2 * rp_bytes);
    float* bufB = bufA + (size_t)n * DIM;

    const int tb = 256;
    build_row_ptr_kernel<<<(n + 1 + tb - 1) / tb, tb, 0, stream>>>(rows,  nnz,  n, rp1);
    build_row_ptr_kernel<<<(n + 1 + tb - 1) / tb, tb, 0, stream>>>(rows2, nnz2, n, rp2);

    const int wpb  = tb / 64;                 // waves per block
    const int grid = (n + wpb - 1) / wpb;

    // e1 = A1 @ e0 ; acc = e0 + e1
    spmm_first_kernel<<<grid, tb, 0, stream>>>(emb, vals, cols, rp1, n, bufA, out);
    // layer 1: e2 from e1 (bufA -> bufB)
    layer_kernel<false><<<grid, tb, 0, stream>>>(emb, bufA, vals2, cols2, rp2, n, bufB, out);
    // layer 2: e3 from e2 (bufB -> bufA)
    layer_kernel<false><<<grid, tb, 0, stream>>>(emb, bufB, vals2, cols2, rp2, n, bufA, out);
    // layer 3 (final): e4 from e3; acc = (acc + e4) / 5
    layer_kernel<true><<<grid, tb, 0, stream>>>(emb, bufA, vals2, cols2, rp2, n, bufB, out);
}

// Round 2
// 933.434 us; speedup vs baseline: 2.2225x; 2.2225x over previous
//
#include <hip/hip_runtime.h>

#define DIM 64

__device__ __forceinline__ int iread(int x, int k) {
    return __builtin_amdgcn_readlane(x, k);
}
__device__ __forceinline__ float fread_lane(float x, int k) {
    return __int_as_float(__builtin_amdgcn_readlane(__float_as_int(x), k));
}

// Wave-per-row sparse row dot: s[lane] = sum_j vals[j] * x[cols[j]*64 + lane].
// (col,val) pairs are pre-loaded 64-at-a-time with coalesced loads, broadcast
// via v_readlane (uniform k -> SGPR), gathers issued 8-deep to hide latency.
__device__ __forceinline__ float spmm_row(const float* __restrict__ x,
                                          const float* __restrict__ vals,
                                          const int*  __restrict__ cols,
                                          int start, int end, int lane)
{
    const float* xl = x + lane;
    float s0 = 0.f, s1 = 0.f, s2 = 0.f, s3 = 0.f;
    for (int base = start; base < end; base += 64) {
        int rem = end - base;
        int cnt = rem < 64 ? rem : 64;
        int c64 = 0; float v64 = 0.f;
        if (lane < cnt) {
            c64 = cols[base + lane];
            v64 = vals[base + lane];
        }
        int k = 0;
        for (; k + 8 <= cnt; k += 8) {
            int   c0 = iread(c64, k),     c1 = iread(c64, k + 1);
            int   c2 = iread(c64, k + 2), c3 = iread(c64, k + 3);
            int   c4 = iread(c64, k + 4), c5 = iread(c64, k + 5);
            int   c6 = iread(c64, k + 6), c7 = iread(c64, k + 7);
            float g0 = xl[(size_t)c0 * DIM];
            float g1 = xl[(size_t)c1 * DIM];
            float g2 = xl[(size_t)c2 * DIM];
            float g3 = xl[(size_t)c3 * DIM];
            float g4 = xl[(size_t)c4 * DIM];
            float g5 = xl[(size_t)c5 * DIM];
            float g6 = xl[(size_t)c6 * DIM];
            float g7 = xl[(size_t)c7 * DIM];
            s0 = fmaf(fread_lane(v64, k),     g0, s0);
            s1 = fmaf(fread_lane(v64, k + 1), g1, s1);
            s2 = fmaf(fread_lane(v64, k + 2), g2, s2);
            s3 = fmaf(fread_lane(v64, k + 3), g3, s3);
            s0 = fmaf(fread_lane(v64, k + 4), g4, s0);
            s1 = fmaf(fread_lane(v64, k + 5), g5, s1);
            s2 = fmaf(fread_lane(v64, k + 6), g6, s2);
            s3 = fmaf(fread_lane(v64, k + 7), g7, s3);
        }
        for (; k < cnt; ++k) {
            int   c = iread(c64, k);
            float v = fread_lane(v64, k);
            s0 = fmaf(v, xl[(size_t)c * DIM], s0);
        }
    }
    return (s0 + s1) + (s2 + s3);
}

// row_ptr[r] = lower_bound(rows, r) over sorted rows.
__global__ void build_row_ptr_kernel(const int* __restrict__ rows, int nnz,
                                     int n, int* __restrict__ row_ptr) {
    int r = blockIdx.x * blockDim.x + threadIdx.x;
    if (r > n) return;
    int lo = 0, hi = nnz;
    while (lo < hi) {
        int mid = (lo + hi) >> 1;
        if (rows[mid] < r) lo = mid + 1; else hi = mid;
    }
    row_ptr[r] = lo;
}

// e1 = A1 @ x0 ; acc = x0 + e1
__global__ __launch_bounds__(256) void spmm_first_kernel(
    const float* __restrict__ x0, const float* __restrict__ vals,
    const int* __restrict__ cols, const int* __restrict__ row_ptr,
    int n, float* __restrict__ e1, float* __restrict__ acc)
{
    int row  = (int)((blockIdx.x * (unsigned)blockDim.x + threadIdx.x) >> 6);
    int lane = threadIdx.x & 63;
    if (row >= n) return;
    float s = spmm_row(x0, vals, cols, row_ptr[row], row_ptr[row + 1], lane);
    size_t o = (size_t)row * DIM + lane;
    e1[o]  = s;
    acc[o] = x0[o] + s;
}

// prop = A2 @ eprev; b = pearson(eprev_row, x0_row);
// enew = b*prop + (1-b)*x0; acc += enew (FINAL: acc = (acc+enew)/5).
template <bool FINAL>
__global__ __launch_bounds__(256) void layer_kernel(
    const float* __restrict__ x0, const float* __restrict__ eprev,
    const float* __restrict__ vals2, const int* __restrict__ cols2,
    const int* __restrict__ row_ptr2, int n,
    float* __restrict__ enew, float* __restrict__ acc)
{
    int row  = (int)((blockIdx.x * (unsigned)blockDim.x + threadIdx.x) >> 6);
    int lane = threadIdx.x & 63;
    if (row >= n) return;
    float prop = spmm_row(eprev, vals2, cols2, row_ptr2[row], row_ptr2[row + 1], lane);

    size_t o  = (size_t)row * DIM + lane;
    float xp = eprev[o];
    float y0 = x0[o];

    float sx = xp, sy = y0;
    #pragma unroll
    for (int m = 1; m < 64; m <<= 1) {
        sx += __shfl_xor(sx, m);
        sy += __shfl_xor(sy, m);
    }
    float mx = sx * (1.f / 64.f), my = sy * (1.f / 64.f);
    float xd = xp - mx, yd = y0 - my;
    float sxy = xd * yd, sxx = xd * xd, syy = yd * yd;
    #pragma unroll
    for (int m = 1; m < 64; m <<= 1) {
        sxy += __shfl_xor(sxy, m);
        sxx += __shfl_xor(sxx, m);
        syy += __shfl_xor(syy, m);
    }
    float den = sqrtf(sxx) * sqrtf(syy);
    den = (den < 1e-7f) ? 1e-7f : den;
    float b  = sxy / den;
    float en = b * prop + (1.f - b) * y0;

    if (!FINAL) {
        enew[o] = en;
        acc[o] += en;
    } else {
        acc[o] = (acc[o] + en) * 0.2f;
    }
}

extern "C" void kernel_launch(void* const* d_in, const int* in_sizes, int n_in,
                              void* d_out, int out_size, void* d_ws, size_t ws_size,
                              hipStream_t stream) {
    const float* emb   = (const float*)d_in[0];
    const float* vals  = (const float*)d_in[1];
    const float* vals2 = (const float*)d_in[2];
    const int*   rows  = (const int*)d_in[3];
    const int*   cols  = (const int*)d_in[4];
    const int*   rows2 = (const int*)d_in[5];
    const int*   cols2 = (const int*)d_in[6];
    // n_layers = 3 (fixed for this problem)

    const int n    = in_sizes[0] / DIM;   // 300000
    const int nnz  = in_sizes[1];         // 4800000
    const int nnz2 = in_sizes[2];

    float* out = (float*)d_out;           // running mean accumulator

    char*  ws       = (char*)d_ws;
    size_t rp_bytes = (((size_t)(n + 1) * sizeof(int)) + 255) & ~(size_t)255;
    int*   rp1  = (int*)ws;
    int*   rp2  = (int*)(ws + rp_bytes);
    float* bufA = (float*)(ws + 2 * rp_bytes);
    float* bufB = bufA + (size_t)n * DIM;

    const int tb = 256;
    build_row_ptr_kernel<<<(n + 1 + tb - 1) / tb, tb, 0, stream>>>(rows,  nnz,  n, rp1);
    build_row_ptr_kernel<<<(n + 1 + tb - 1) / tb, tb, 0, stream>>>(rows2, nnz2, n, rp2);

    const int wpb  = tb / 64;
    const int grid = (n + wpb - 1) / wpb;

    spmm_first_kernel<<<grid, tb, 0, stream>>>(emb, vals, cols, rp1, n, bufA, out);
    layer_kernel<false><<<grid, tb, 0, stream>>>(emb, bufA, vals2, cols2, rp2, n, bufB, out);
    layer_kernel<false><<<grid, tb, 0, stream>>>(emb, bufB, vals2, cols2, rp2, n, bufA, out);
    layer_kernel<true><<<grid, tb, 0, stream>>>(emb, bufA, vals2, cols2, rp2, n, bufB, out);
}

// Round 3
// 857.455 us; speedup vs baseline: 2.4195x; 1.0886x over previous
//
#include <hip/hip_runtime.h>

#define DIM 64

typedef __attribute__((ext_vector_type(4))) float f4;

// sum across the 4 quarters (lanes l, l^16, l^32, l^48)
__device__ __forceinline__ float qsum(float v) {
    v += __shfl_xor(v, 16, 64);
    v += __shfl_xor(v, 32, 64);
    return v;
}
// sum within each 16-lane group (inputs replicated across quarters -> full row sum)
__device__ __forceinline__ float rsum16(float v) {
    v += __shfl_xor(v, 1, 64);
    v += __shfl_xor(v, 2, 64);
    v += __shfl_xor(v, 4, 64);
    v += __shfl_xor(v, 8, 64);
    return v;
}

// Wave-per-row SpMM, quarter-wave float4 gathers: per round of 16 nnz,
// each quarter (16 lanes) gathers one nnz's full 256B row via dwordx4.
// Returns per-lane f4 = output dims [4t .. 4t+3], t = lane&15 (replicated
// across quarters).
__device__ __forceinline__ f4 spmm_row_f4(const float* __restrict__ x,
                                          const float* __restrict__ vals,
                                          const int*  __restrict__ cols,
                                          int start, int end, int lane)
{
    const int q = lane >> 4, t = lane & 15;
    f4 a0 = (f4)0.f, a1 = (f4)0.f, a2 = (f4)0.f, a3 = (f4)0.f;
    for (int base = start; base < end; base += 64) {
        int cnt = end - base; if (cnt > 64) cnt = 64;
        int   cl = 0; float vl = 0.f;
        if (lane < cnt) {
            cl = __builtin_nontemporal_load(cols + base + lane);
            vl = __builtin_nontemporal_load(vals + base + lane);
        }
        int m = cnt - 1;
        for (int k = 0; k < cnt; k += 16) {
            int i0 = k + q, i1 = k + 4 + q, i2 = k + 8 + q, i3 = k + 12 + q;
            int j0 = i0 > m ? m : i0, j1 = i1 > m ? m : i1;
            int j2 = i2 > m ? m : i2, j3 = i3 > m ? m : i3;
            int c0 = __shfl(cl, j0, 64), c1 = __shfl(cl, j1, 64);
            int c2 = __shfl(cl, j2, 64), c3 = __shfl(cl, j3, 64);
            float v0 = __shfl(vl, j0, 64), v1 = __shfl(vl, j1, 64);
            float v2 = __shfl(vl, j2, 64), v3 = __shfl(vl, j3, 64);
            if (i0 > m) v0 = 0.f;
            if (i1 > m) v1 = 0.f;
            if (i2 > m) v2 = 0.f;
            if (i3 > m) v3 = 0.f;
            const f4* p0 = (const f4*)(x + (size_t)c0 * DIM) + t;
            const f4* p1 = (const f4*)(x + (size_t)c1 * DIM) + t;
            const f4* p2 = (const f4*)(x + (size_t)c2 * DIM) + t;
            const f4* p3 = (const f4*)(x + (size_t)c3 * DIM) + t;
            f4 g0 = *p0; f4 g1 = *p1; f4 g2 = *p2; f4 g3 = *p3;
            a0 += v0 * g0;
            a1 += v1 * g1;
            a2 += v2 * g2;
            a3 += v3 * g3;
        }
    }
    f4 s = (a0 + a1) + (a2 + a3);
    s.x = qsum(s.x); s.y = qsum(s.y); s.z = qsum(s.z); s.w = qsum(s.w);
    return s;
}

// row_ptr[r] = lower_bound(rows, r) over sorted rows.
__global__ void build_row_ptr_kernel(const int* __restrict__ rows, int nnz,
                                     int n, int* __restrict__ row_ptr) {
    int r = blockIdx.x * blockDim.x + threadIdx.x;
    if (r > n) return;
    int lo = 0, hi = nnz;
    while (lo < hi) {
        int mid = (lo + hi) >> 1;
        if (rows[mid] < r) lo = mid + 1; else hi = mid;
    }
    row_ptr[r] = lo;
}

// e1 = A1 @ x0 ; acc = x0 + e1.  x0 is the gather table here: keep cached.
__global__ __launch_bounds__(256) void spmm_first_kernel(
    const float* __restrict__ x0, const float* __restrict__ vals,
    const int* __restrict__ cols, const int* __restrict__ row_ptr,
    int n, float* __restrict__ e1, float* __restrict__ acc)
{
    int row  = (int)((blockIdx.x * (unsigned)blockDim.x + threadIdx.x) >> 6);
    int lane = threadIdx.x & 63;
    if (row >= n) return;
    f4 s = spmm_row_f4(x0, vals, cols, row_ptr[row], row_ptr[row + 1], lane);
    int q = lane >> 4, t = lane & 15;
    size_t o4 = (size_t)row * DIM + (size_t)t * 4;
    if (q == 0) {
        f4 x = *(const f4*)(x0 + o4);
        *(f4*)(e1 + o4)  = s;
        *(f4*)(acc + o4) = x + s;
    }
}

// prop = A2 @ eprev; b = pearson(eprev_row, x0_row);
// enew = b*prop + (1-b)*x0; acc += enew (FINAL: acc = (acc+enew)*0.2).
template <bool FINAL>
__global__ __launch_bounds__(256) void layer_kernel(
    const float* __restrict__ x0, const float* __restrict__ eprev,
    const float* __restrict__ vals2, const int* __restrict__ cols2,
    const int* __restrict__ row_ptr2, int n,
    float* __restrict__ enew, float* __restrict__ acc)
{
    int row  = (int)((blockIdx.x * (unsigned)blockDim.x + threadIdx.x) >> 6);
    int lane = threadIdx.x & 63;
    if (row >= n) return;
    f4 prop = spmm_row_f4(eprev, vals2, cols2, row_ptr2[row], row_ptr2[row + 1], lane);

    int q = lane >> 4, t = lane & 15;
    size_t o4 = (size_t)row * DIM + (size_t)t * 4;
    f4 xp = *(const f4*)(eprev + o4);                       // table: cached
    f4 y0 = __builtin_nontemporal_load((const f4*)(x0 + o4)); // stream: nt

    float px  = (xp.x + xp.y) + (xp.z + xp.w);
    float py  = (y0.x + y0.y) + (y0.z + y0.w);
    float pxx = (xp.x*xp.x + xp.y*xp.y) + (xp.z*xp.z + xp.w*xp.w);
    float pyy = (y0.x*y0.x + y0.y*y0.y) + (y0.z*y0.z + y0.w*y0.w);
    float pxy = (xp.x*y0.x + xp.y*y0.y) + (xp.z*y0.z + xp.w*y0.w);
    float Sx  = rsum16(px),  Sy  = rsum16(py);
    float Sxx = rsum16(pxx), Syy = rsum16(pyy), Sxy = rsum16(pxy);

    float mx = Sx * (1.f / 64.f), my = Sy * (1.f / 64.f);
    float num = Sxy - 64.f * mx * my;
    float vx  = Sxx - 64.f * mx * mx;
    float vy  = Syy - 64.f * my * my;
    float den = sqrtf(fmaxf(vx, 0.f)) * sqrtf(fmaxf(vy, 0.f));
    den = (den < 1e-7f) ? 1e-7f : den;
    float b = num / den;

    f4 en = b * prop + (1.f - b) * y0;

    if (q == 0) {
        f4* accp = (f4*)(acc + o4);
        if (!FINAL) {
            *(f4*)(enew + o4) = en;
            f4 a = *accp;
            *accp = a + en;
        } else {
            f4 a = *accp;
            *accp = (a + en) * 0.2f;
        }
    }
}

extern "C" void kernel_launch(void* const* d_in, const int* in_sizes, int n_in,
                              void* d_out, int out_size, void* d_ws, size_t ws_size,
                              hipStream_t stream) {
    const float* emb   = (const float*)d_in[0];
    const float* vals  = (const float*)d_in[1];
    const float* vals2 = (const float*)d_in[2];
    const int*   rows  = (const int*)d_in[3];
    const int*   cols  = (const int*)d_in[4];
    const int*   rows2 = (const int*)d_in[5];
    const int*   cols2 = (const int*)d_in[6];
    // n_layers = 3 (fixed for this problem)

    const int n    = in_sizes[0] / DIM;   // 300000
    const int nnz  = in_sizes[1];         // 4800000
    const int nnz2 = in_sizes[2];

    float* out = (float*)d_out;           // running mean accumulator

    char*  ws       = (char*)d_ws;
    size_t rp_bytes = (((size_t)(n + 1) * sizeof(int)) + 255) & ~(size_t)255;
    int*   rp1  = (int*)ws;
    int*   rp2  = (int*)(ws + rp_bytes);
    float* bufA = (float*)(ws + 2 * rp_bytes);
    float* bufB = bufA + (size_t)n * DIM;

    const int tb = 256;
    build_row_ptr_kernel<<<(n + 1 + tb - 1) / tb, tb, 0, stream>>>(rows,  nnz,  n, rp1);
    build_row_ptr_kernel<<<(n + 1 + tb - 1) / tb, tb, 0, stream>>>(rows2, nnz2, n, rp2);

    const int wpb  = tb / 64;
    const int grid = (n + wpb - 1) / wpb;

    spmm_first_kernel<<<grid, tb, 0, stream>>>(emb, vals, cols, rp1, n, bufA, out);
    layer_kernel<false><<<grid, tb, 0, stream>>>(emb, bufA, vals2, cols2, rp2, n, bufB, out);
    layer_kernel<false><<<grid, tb, 0, stream>>>(emb, bufB, vals2, cols2, rp2, n, bufA, out);
    layer_kernel<true><<<grid, tb, 0, stream>>>(emb, bufA, vals2, cols2, rp2, n, bufB, out);
}

// Round 4
// 665.342 us; speedup vs baseline: 3.1181x; 1.2887x over previous
//
#include <hip/hip_runtime.h>

#define DIM 64

typedef __attribute__((ext_vector_type(4))) float f4;
typedef __attribute__((ext_vector_type(4))) unsigned int u4;

// ---- bf16 helpers (bit-level, RNE) ----
__device__ __forceinline__ float bflo(unsigned u) { return __uint_as_float(u << 16); }
__device__ __forceinline__ float bfhi(unsigned u) { return __uint_as_float(u & 0xffff0000u); }
__device__ __forceinline__ unsigned bfr(float f) {
    unsigned u = __float_as_uint(f);
    return (u + 0x7fffu + ((u >> 16) & 1u)) >> 16;
}
__device__ __forceinline__ unsigned packbf(float e, float o) { return bfr(e) | (bfr(o) << 16); }

// row_ptr[r] = lower_bound(rows, r) over sorted rows.
__global__ void build_row_ptr_kernel(const int* __restrict__ rows, int nnz,
                                     int n, int* __restrict__ row_ptr) {
    int r = blockIdx.x * blockDim.x + threadIdx.x;
    if (r > n) return;
    int lo = 0, hi = nnz;
    while (lo < hi) {
        int mid = (lo + hi) >> 1;
        if (rows[mid] < r) lo = mid + 1; else hi = mid;
    }
    row_ptr[r] = lo;
}

// f32 -> packed bf16 table, 8 elems per thread.
__global__ void cvt_bf16_kernel(const float* __restrict__ in,
                                unsigned int* __restrict__ out, int n8) {
    int i = blockIdx.x * blockDim.x + threadIdx.x;
    if (i >= n8) return;
    const f4* p = (const f4*)in + 2 * (size_t)i;
    f4 a = p[0], b = p[1];
    u4 o;
    o.x = packbf(a.x, a.y); o.y = packbf(a.z, a.w);
    o.z = packbf(b.x, b.y); o.w = packbf(b.z, b.w);
    ((u4*)out)[i] = o;
}

// MODE 0: e1 = A1 @ t0                      -> enew (bf16)
// MODE 1: prop = A2@eprev; b=pearson(eprev,t0); en = b*prop+(1-b)*t0 -> enew
// MODE 2: as MODE1 with y0 = emb(f32); out = (emb + e1 + e2 + eprev + en)/5
//
// Wave per row. 8-lane groups: g = lane>>3 handles nnz (8k+g), j = lane&7
// handles dims 8j..8j+7 (one dwordx4 of the 128B bf16 row per lane).
template <int MODE>
__global__ __launch_bounds__(256) void layer_kernel(
    const float* __restrict__ emb,
    const unsigned short* __restrict__ t0,
    const unsigned short* __restrict__ eprev,
    const float* __restrict__ vals, const int* __restrict__ cols,
    const int* __restrict__ rp, int n,
    unsigned short* __restrict__ enew,
    const unsigned short* __restrict__ e1t,
    const unsigned short* __restrict__ e2t,
    float* __restrict__ out)
{
    int lane = threadIdx.x & 63;
    int row  = (int)((blockIdx.x * (unsigned)blockDim.x + threadIdx.x) >> 6);
    if (row >= n) return;
    int start = __builtin_amdgcn_readfirstlane(rp[row]);
    int end   = __builtin_amdgcn_readfirstlane(rp[row + 1]);
    const int j = lane & 7;
    const int g = lane >> 3;

    const unsigned short* tbl = (MODE == 0) ? t0 : eprev;

    float a[8] = {0.f, 0.f, 0.f, 0.f, 0.f, 0.f, 0.f, 0.f};

    for (int base = start; base < end; base += 64) {
        int cnt = end - base; if (cnt > 64) cnt = 64;
        // sigma-permuted preload: lane l holds (col,val)[ (l&7)*8 + (l>>3) ]
        int sig = ((lane & 7) << 3) | (lane >> 3);
        int c = 0; float v = 0.f;
        if (sig < cnt) {
            c = __builtin_nontemporal_load(cols + base + sig);
            v = __builtin_nontemporal_load(vals + base + sig);
        }
        // round r: group g consumes nnz 8r+g; broadcast via ds_swizzle
        // src lane = (l & 0x38) | r  -> BitMode offset (r<<5)|0x18.
#define ROUND(r)                                                              \
        if ((r) * 8 < cnt) {                                                  \
            int   cr = __builtin_amdgcn_ds_swizzle(c, ((r) << 5) | 0x18);     \
            float vr = __int_as_float(                                        \
                __builtin_amdgcn_ds_swizzle(__float_as_int(v), ((r) << 5) | 0x18)); \
            u4 gd = *((const u4*)(tbl + ((size_t)(unsigned)cr << 6)) + j);    \
            a[0] = fmaf(vr, bflo(gd.x), a[0]);                                \
            a[1] = fmaf(vr, bfhi(gd.x), a[1]);                                \
            a[2] = fmaf(vr, bflo(gd.y), a[2]);                                \
            a[3] = fmaf(vr, bfhi(gd.y), a[3]);                                \
            a[4] = fmaf(vr, bflo(gd.z), a[4]);                                \
            a[5] = fmaf(vr, bfhi(gd.z), a[5]);                                \
            a[6] = fmaf(vr, bflo(gd.w), a[6]);                                \
            a[7] = fmaf(vr, bfhi(gd.w), a[7]);                                \
        }
        ROUND(0) ROUND(1) ROUND(2) ROUND(3) ROUND(4) ROUND(5) ROUND(6) ROUND(7)
#undef ROUND
    }

    // sum partials across the 8 groups -> full prop for dims 8j..8j+7
    #pragma unroll
    for (int i = 0; i < 8; ++i) {
        a[i] += __shfl_xor(a[i], 8, 64);
        a[i] += __shfl_xor(a[i], 16, 64);
        a[i] += __shfl_xor(a[i], 32, 64);
    }

    size_t rowo = (size_t)row << 6;  // *DIM

    if (MODE == 0) {
        if (g == 0) {
            u4 o;
            o.x = packbf(a[0], a[1]); o.y = packbf(a[2], a[3]);
            o.z = packbf(a[4], a[5]); o.w = packbf(a[6], a[7]);
            *((u4*)(enew + rowo) + j) = o;
        }
        return;
    }

    // xp = eprev row, y0 = t0 (bf16) or emb (f32, MODE 2)
    u4 xr = *((const u4*)(eprev + rowo) + j);
    float xp[8] = { bflo(xr.x), bfhi(xr.x), bflo(xr.y), bfhi(xr.y),
                    bflo(xr.z), bfhi(xr.z), bflo(xr.w), bfhi(xr.w) };
    float y0[8];
    if (MODE == 2) {
        const f4* ep = (const f4*)(emb + rowo) + 2 * j;
        f4 ea = ep[0], eb = ep[1];
        y0[0] = ea.x; y0[1] = ea.y; y0[2] = ea.z; y0[3] = ea.w;
        y0[4] = eb.x; y0[5] = eb.y; y0[6] = eb.z; y0[7] = eb.w;
    } else {
        u4 yr = *((const u4*)(t0 + rowo) + j);
        y0[0] = bflo(yr.x); y0[1] = bfhi(yr.x); y0[2] = bflo(yr.y); y0[3] = bfhi(yr.y);
        y0[4] = bflo(yr.z); y0[5] = bfhi(yr.z); y0[6] = bflo(yr.w); y0[7] = bfhi(yr.w);
    }

    // Pearson over 64 dims: per-lane partials over 8 dims, reduce over j.
    float sx = 0.f, sy = 0.f, sxx = 0.f, syy = 0.f, sxy = 0.f;
    #pragma unroll
    for (int i = 0; i < 8; ++i) {
        sx += xp[i]; sy += y0[i];
        sxx = fmaf(xp[i], xp[i], sxx);
        syy = fmaf(y0[i], y0[i], syy);
        sxy = fmaf(xp[i], y0[i], sxy);
    }
    #pragma unroll
    for (int m = 1; m < 8; m <<= 1) {
        sx  += __shfl_xor(sx,  m, 64);
        sy  += __shfl_xor(sy,  m, 64);
        sxx += __shfl_xor(sxx, m, 64);
        syy += __shfl_xor(syy, m, 64);
        sxy += __shfl_xor(sxy, m, 64);
    }
    float mx = sx * (1.f / 64.f), my = sy * (1.f / 64.f);
    float num = sxy - 64.f * mx * my;
    float vx  = sxx - 64.f * mx * mx;
    float vy  = syy - 64.f * my * my;
    float den = sqrtf(fmaxf(vx, 0.f)) * sqrtf(fmaxf(vy, 0.f));
    den = (den < 1e-7f) ? 1e-7f : den;
    float b  = num / den;
    float ob = 1.f - b;

    float en[8];
    #pragma unroll
    for (int i = 0; i < 8; ++i) en[i] = b * a[i] + ob * y0[i];

    if (MODE == 1) {
        if (g == 0) {
            u4 o;
            o.x = packbf(en[0], en[1]); o.y = packbf(en[2], en[3]);
            o.z = packbf(en[4], en[5]); o.w = packbf(en[6], en[7]);
            *((u4*)(enew + rowo) + j) = o;
        }
    } else {
        // fused mean: out = (emb + e1 + e2 + eprev + en) / 5
        u4 r1 = *((const u4*)(e1t + rowo) + j);
        u4 r2 = *((const u4*)(e2t + rowo) + j);
        float s[8];
        s[0] = y0[0] + bflo(r1.x) + bflo(r2.x) + xp[0] + en[0];
        s[1] = y0[1] + bfhi(r1.x) + bfhi(r2.x) + xp[1] + en[1];
        s[2] = y0[2] + bflo(r1.y) + bflo(r2.y) + xp[2] + en[2];
        s[3] = y0[3] + bfhi(r1.y) + bfhi(r2.y) + xp[3] + en[3];
        s[4] = y0[4] + bflo(r1.z) + bflo(r2.z) + xp[4] + en[4];
        s[5] = y0[5] + bfhi(r1.z) + bfhi(r2.z) + xp[5] + en[5];
        s[6] = y0[6] + bflo(r1.w) + bflo(r2.w) + xp[6] + en[6];
        s[7] = y0[7] + bfhi(r1.w) + bfhi(r2.w) + xp[7] + en[7];
        if (g == 0) {
            f4 o0 = { s[0] * 0.2f, s[1] * 0.2f, s[2] * 0.2f, s[3] * 0.2f };
            f4 o1 = { s[4] * 0.2f, s[5] * 0.2f, s[6] * 0.2f, s[7] * 0.2f };
            f4* op = (f4*)(out + rowo) + 2 * j;
            op[0] = o0; op[1] = o1;
        }
    }
}

extern "C" void kernel_launch(void* const* d_in, const int* in_sizes, int n_in,
                              void* d_out, int out_size, void* d_ws, size_t ws_size,
                              hipStream_t stream) {
    const float* emb   = (const float*)d_in[0];
    const float* vals  = (const float*)d_in[1];
    const float* vals2 = (const float*)d_in[2];
    const int*   rows  = (const int*)d_in[3];
    const int*   cols  = (const int*)d_in[4];
    const int*   rows2 = (const int*)d_in[5];
    const int*   cols2 = (const int*)d_in[6];
    // n_layers = 3 (fixed for this problem)

    const int n    = in_sizes[0] / DIM;   // 300000
    const int nnz  = in_sizes[1];         // 4800000
    const int nnz2 = in_sizes[2];

    float* out = (float*)d_out;

    // ws: rp1 | rp2 | T0 | E1 | E2 | E3   (2*1.2MB + 4*38.4MB = 156.0MB)
    char*  ws       = (char*)d_ws;
    size_t rp_bytes = (((size_t)(n + 1) * sizeof(int)) + 255) & ~(size_t)255;
    size_t tb_bytes = (size_t)n * DIM * sizeof(unsigned short);
    int* rp1 = (int*)ws;
    int* rp2 = (int*)(ws + rp_bytes);
    unsigned short* T0 = (unsigned short*)(ws + 2 * rp_bytes);
    unsigned short* E1 = (unsigned short*)((char*)T0 + tb_bytes);
    unsigned short* E2 = (unsigned short*)((char*)E1 + tb_bytes);
    unsigned short* E3 = (unsigned short*)((char*)E2 + tb_bytes);

    const int tb = 256;
    build_row_ptr_kernel<<<(n + 1 + tb - 1) / tb, tb, 0, stream>>>(rows,  nnz,  n, rp1);
    build_row_ptr_kernel<<<(n + 1 + tb - 1) / tb, tb, 0, stream>>>(rows2, nnz2, n, rp2);

    const int n8 = n * DIM / 8;
    cvt_bf16_kernel<<<(n8 + tb - 1) / tb, tb, 0, stream>>>(emb, (unsigned int*)T0, n8);

    const int grid = (n + 3) / 4;  // 4 waves (rows) per 256-thread block
    // e1 = A1 @ t0
    layer_kernel<0><<<grid, tb, 0, stream>>>(emb, T0, T0, vals, cols, rp1, n,
                                             E1, T0, T0, out);
    // e2 from e1
    layer_kernel<1><<<grid, tb, 0, stream>>>(emb, T0, E1, vals2, cols2, rp2, n,
                                             E2, T0, T0, out);
    // e3 from e2
    layer_kernel<1><<<grid, tb, 0, stream>>>(emb, T0, E2, vals2, cols2, rp2, n,
                                             E3, T0, T0, out);
    // final: e4 from e3, fused mean -> out
    layer_kernel<2><<<grid, tb, 0, stream>>>(emb, T0, E3, vals2, cols2, rp2, n,
                                             E3, E1, E2, out);
}

// Round 5
// 653.745 us; speedup vs baseline: 3.1734x; 1.0177x over previous
//
#include <hip/hip_runtime.h>

#define DIM 64

typedef __attribute__((ext_vector_type(4))) float f4;
typedef __attribute__((ext_vector_type(2))) float f2;
typedef __attribute__((ext_vector_type(4))) unsigned int u4;

#define SEL_LO 0x01000504u   // [gb.lo16 : ga.lo16]
#define SEL_HI 0x03020706u   // [gb.hi16 : ga.hi16]
#define ONE2   0x3f803f80u   // bf16 pair (1.0, 1.0)

// ---- bf16 helpers (bit-level, RNE) ----
__device__ __forceinline__ float bflo(unsigned u) { return __uint_as_float(u << 16); }
__device__ __forceinline__ float bfhi(unsigned u) { return __uint_as_float(u & 0xffff0000u); }
__device__ __forceinline__ unsigned bfr(float f) {
    unsigned u = __float_as_uint(f);
    return (u + 0x7fffu + ((u >> 16) & 1u)) >> 16;
}
__device__ __forceinline__ unsigned packbf(float e, float o) { return bfr(e) | (bfr(o) << 16); }

// D = a.lo*b.lo + a.hi*b.hi + c   (bf16 pairs, f32 accumulate)
__device__ __forceinline__ float dot2bf(unsigned a, unsigned b, float c) {
    float d;
    asm("v_dot2_f32_bf16 %0, %1, %2, %3" : "=v"(d) : "v"(a), "v"(b), "v"(c));
    return d;
}

// row_ptr[r] = lower_bound(rows, r) over sorted rows.
__global__ void build_row_ptr_kernel(const int* __restrict__ rows, int nnz,
                                     int n, int* __restrict__ row_ptr) {
    int r = blockIdx.x * blockDim.x + threadIdx.x;
    if (r > n) return;
    int lo = 0, hi = nnz;
    while (lo < hi) {
        int mid = (lo + hi) >> 1;
        if (rows[mid] < r) lo = mid + 1; else hi = mid;
    }
    row_ptr[r] = lo;
}

// f32 -> packed bf16 table, 8 elems per thread.
__global__ void cvt_bf16_kernel(const float* __restrict__ in,
                                unsigned int* __restrict__ out, int n8) {
    int i = blockIdx.x * blockDim.x + threadIdx.x;
    if (i >= n8) return;
    const f4* p = (const f4*)in + 2 * (size_t)i;
    f4 a = p[0], b = p[1];
    u4 o;
    o.x = packbf(a.x, a.y); o.y = packbf(a.z, a.w);
    o.z = packbf(b.x, b.y); o.w = packbf(b.z, b.w);
    ((u4*)out)[i] = o;
}

// MODE 0: e1 = A1 @ t0 -> enew; also per-row y-stats (my, sqrt(vy)) from t0.
// MODE 1: prop = A2@eprev; b = pearson(eprev, t0); en = b*prop+(1-b)*t0 -> enew
// MODE 2: as MODE1 with y0 = emb(f32); out = (emb + e1 + e2 + eprev + en)/5
//
// Wave per row. 8 groups (g = lane>>3) each handle one nnz-PAIR per round;
// j = lane&7 owns dims 8j..8j+7 (one dwordx4 of the 128B bf16 row).
template <int MODE>
__global__ __launch_bounds__(256) void layer_kernel(
    const float* __restrict__ emb,
    const unsigned short* __restrict__ t0,
    const unsigned short* __restrict__ eprev,
    const float* __restrict__ vals, const int* __restrict__ cols,
    const int* __restrict__ rp, int n,
    unsigned short* __restrict__ enew,
    const unsigned short* __restrict__ e1t,
    const unsigned short* __restrict__ e2t,
    f2* __restrict__ stats,
    float* __restrict__ out)
{
    const int lane = threadIdx.x & 63;
    const int row  = (int)((blockIdx.x * (unsigned)blockDim.x + threadIdx.x) >> 6);
    if (row >= n) return;
    const int start = __builtin_amdgcn_readfirstlane(rp[row]);
    const int end   = __builtin_amdgcn_readfirstlane(rp[row + 1]);
    const int j = lane & 7;
    const unsigned joff = (unsigned)(j << 4);   // byte offset of dim block in a row

    const char* tb8 = (const char*)((MODE == 0) ? t0 : eprev);

    float acc[8] = {0.f, 0.f, 0.f, 0.f, 0.f, 0.f, 0.f, 0.f};

    for (int b0 = (start & ~1); b0 < end; b0 += 64) {
        int cnt = end - b0; if (cnt > 64) cnt = 64;
        // col preload: lane l holds cols[b0 + 16*(l&3) + 2*(l>>3) + ((l>>2)&1)]
        int e_c  = ((lane & 3) << 4) | ((lane >> 3) << 1) | ((lane >> 2) & 1);
        int cidx = b0 + e_c;
        int c = 0;
        if (cidx < end) c = __builtin_nontemporal_load(cols + cidx);
        // val-pair preload: lane l holds pair pr = 8*(l&3) + (l>>3) (bit2 dup)
        int pr = ((lane & 3) << 3) | (lane >> 3);
        int gi = b0 + 2 * pr;
        float v0 = 0.f, v1 = 0.f;
        if (gi < end)     v0 = __builtin_nontemporal_load(vals + gi);
        if (gi + 1 < end) v1 = __builtin_nontemporal_load(vals + gi + 1);
        if (gi < start)   v0 = 0.f;   // first-block alignment padding
        unsigned vp = bfr(v0) | (bfr(v1) << 16);

        // round r: group g handles pair 8r+g (nnz b0+16r+2g, +1).
        // swizzle src = (l&0x18)|or within 32-lane half (bit5 preserved).
#define PROUND(r) if (cnt > 16 * (r)) {                                         \
        int ce = __builtin_amdgcn_ds_swizzle(c, ((r) << 5) | 0x18);             \
        int co = __builtin_amdgcn_ds_swizzle(c, (((r) | 4) << 5) | 0x18);       \
        unsigned vv = (unsigned)__builtin_amdgcn_ds_swizzle((int)vp,            \
                                                    ((r) << 5) | 0x18);         \
        u4 ga = *(const u4*)(tb8 + ((((unsigned)ce) << 7) + joff));             \
        u4 gb = *(const u4*)(tb8 + ((((unsigned)co) << 7) + joff));             \
        acc[0] = dot2bf(__builtin_amdgcn_perm(ga.x, gb.x, SEL_LO), vv, acc[0]); \
        acc[1] = dot2bf(__builtin_amdgcn_perm(ga.x, gb.x, SEL_HI), vv, acc[1]); \
        acc[2] = dot2bf(__builtin_amdgcn_perm(ga.y, gb.y, SEL_LO), vv, acc[2]); \
        acc[3] = dot2bf(__builtin_amdgcn_perm(ga.y, gb.y, SEL_HI), vv, acc[3]); \
        acc[4] = dot2bf(__builtin_amdgcn_perm(ga.z, gb.z, SEL_LO), vv, acc[4]); \
        acc[5] = dot2bf(__builtin_amdgcn_perm(ga.z, gb.z, SEL_HI), vv, acc[5]); \
        acc[6] = dot2bf(__builtin_amdgcn_perm(ga.w, gb.w, SEL_LO), vv, acc[6]); \
        acc[7] = dot2bf(__builtin_amdgcn_perm(ga.w, gb.w, SEL_HI), vv, acc[7]); \
    }
        PROUND(0) PROUND(1) PROUND(2) PROUND(3)
#undef PROUND
    }

    // sum partials across the 8 groups
    #pragma unroll
    for (int i = 0; i < 8; ++i) {
        acc[i] += __shfl_xor(acc[i], 8, 64);
        acc[i] += __shfl_xor(acc[i], 16, 64);
        acc[i] += __shfl_xor(acc[i], 32, 64);
    }

    size_t rowo = (size_t)row << 6;  // *DIM

    if (MODE == 0) {
        // y-stats of t0 row (loop-invariant across layers)
        u4 yr = *((const u4*)(t0 + rowo) + j);
        float sy  = dot2bf(yr.x, ONE2,
                    dot2bf(yr.y, ONE2, dot2bf(yr.z, ONE2, dot2bf(yr.w, ONE2, 0.f))));
        float syy = dot2bf(yr.x, yr.x,
                    dot2bf(yr.y, yr.y, dot2bf(yr.z, yr.z, dot2bf(yr.w, yr.w, 0.f))));
        #pragma unroll
        for (int m = 1; m < 8; m <<= 1) {
            sy  += __shfl_xor(sy,  m, 64);
            syy += __shfl_xor(syy, m, 64);
        }
        float my  = sy * (1.f / 64.f);
        float vy  = syy - sy * my;
        float svy = sqrtf(fmaxf(vy, 0.f));
        if (lane == 0) { f2 s; s.x = my; s.y = svy; stats[row] = s; }
        if (lane < 8) {
            u4 o;
            o.x = packbf(acc[0], acc[1]); o.y = packbf(acc[2], acc[3]);
            o.z = packbf(acc[4], acc[5]); o.w = packbf(acc[6], acc[7]);
            *((u4*)(enew + rowo) + j) = o;
        }
        return;
    }

    // Pearson(eprev_row, t0_row) with precomputed y-stats.
    u4 xr = *((const u4*)(eprev + rowo) + j);
    u4 yr = *((const u4*)(t0 + rowo) + j);
    float sx  = dot2bf(xr.x, ONE2,
                dot2bf(xr.y, ONE2, dot2bf(xr.z, ONE2, dot2bf(xr.w, ONE2, 0.f))));
    float sxx = dot2bf(xr.x, xr.x,
                dot2bf(xr.y, xr.y, dot2bf(xr.z, xr.z, dot2bf(xr.w, xr.w, 0.f))));
    float sxy = dot2bf(xr.x, yr.x,
                dot2bf(xr.y, yr.y, dot2bf(xr.z, yr.z, dot2bf(xr.w, yr.w, 0.f))));
    #pragma unroll
    for (int m = 1; m < 8; m <<= 1) {
        sx  += __shfl_xor(sx,  m, 64);
        sxx += __shfl_xor(sxx, m, 64);
        sxy += __shfl_xor(sxy, m, 64);
    }
    f2 st = stats[row];
    float mx  = sx * (1.f / 64.f);
    float num = sxy - sx * st.x;          // sxy - 64*mx*my
    float vx  = sxx - sx * mx;            // sxx - 64*mx*mx
    float den = sqrtf(fmaxf(vx, 0.f)) * st.y;
    den = fmaxf(den, 1e-7f);
    float b  = num / den;
    float ob = 1.f - b;

    if (MODE == 1) {
        float y0[8] = { bflo(yr.x), bfhi(yr.x), bflo(yr.y), bfhi(yr.y),
                        bflo(yr.z), bfhi(yr.z), bflo(yr.w), bfhi(yr.w) };
        float en[8];
        #pragma unroll
        for (int i = 0; i < 8; ++i) en[i] = b * acc[i] + ob * y0[i];
        if (lane < 8) {
            u4 o;
            o.x = packbf(en[0], en[1]); o.y = packbf(en[2], en[3]);
            o.z = packbf(en[4], en[5]); o.w = packbf(en[6], en[7]);
            *((u4*)(enew + rowo) + j) = o;
        }
    } else {
        const f4* ep = (const f4*)(emb + rowo) + 2 * j;
        f4 ea = ep[0], eb = ep[1];
        float y0[8] = { ea.x, ea.y, ea.z, ea.w, eb.x, eb.y, eb.z, eb.w };
        float xp[8] = { bflo(xr.x), bfhi(xr.x), bflo(xr.y), bfhi(xr.y),
                        bflo(xr.z), bfhi(xr.z), bflo(xr.w), bfhi(xr.w) };
        u4 r1 = *((const u4*)(e1t + rowo) + j);
        u4 r2 = *((const u4*)(e2t + rowo) + j);
        float s[8];
        s[0] = y0[0] + bflo(r1.x) + bflo(r2.x) + xp[0] + (b * acc[0] + ob * y0[0]);
        s[1] = y0[1] + bfhi(r1.x) + bfhi(r2.x) + xp[1] + (b * acc[1] + ob * y0[1]);
        s[2] = y0[2] + bflo(r1.y) + bflo(r2.y) + xp[2] + (b * acc[2] + ob * y0[2]);
        s[3] = y0[3] + bfhi(r1.y) + bfhi(r2.y) + xp[3] + (b * acc[3] + ob * y0[3]);
        s[4] = y0[4] + bflo(r1.z) + bflo(r2.z) + xp[4] + (b * acc[4] + ob * y0[4]);
        s[5] = y0[5] + bfhi(r1.z) + bfhi(r2.z) + xp[5] + (b * acc[5] + ob * y0[5]);
        s[6] = y0[6] + bflo(r1.w) + bflo(r2.w) + xp[6] + (b * acc[6] + ob * y0[6]);
        s[7] = y0[7] + bfhi(r1.w) + bfhi(r2.w) + xp[7] + (b * acc[7] + ob * y0[7]);
        if (lane < 8) {
            f4 o0 = { s[0] * 0.2f, s[1] * 0.2f, s[2] * 0.2f, s[3] * 0.2f };
            f4 o1 = { s[4] * 0.2f, s[5] * 0.2f, s[6] * 0.2f, s[7] * 0.2f };
            f4* op = (f4*)(out + rowo) + 2 * j;
            op[0] = o0; op[1] = o1;
        }
    }
}

extern "C" void kernel_launch(void* const* d_in, const int* in_sizes, int n_in,
                              void* d_out, int out_size, void* d_ws, size_t ws_size,
                              hipStream_t stream) {
    const float* emb   = (const float*)d_in[0];
    const float* vals  = (const float*)d_in[1];
    const float* vals2 = (const float*)d_in[2];
    const int*   rows  = (const int*)d_in[3];
    const int*   cols  = (const int*)d_in[4];
    const int*   rows2 = (const int*)d_in[5];
    const int*   cols2 = (const int*)d_in[6];
    // n_layers = 3 (fixed for this problem)

    const int n    = in_sizes[0] / DIM;   // 300000
    const int nnz  = in_sizes[1];         // 4800000
    const int nnz2 = in_sizes[2];

    float* out = (float*)d_out;

    // ws: rp1 | rp2 | ST | T0 | E1 | E2 | E3  (~158.4 MB)
    char*  ws       = (char*)d_ws;
    size_t rp_bytes = (((size_t)(n + 1) * sizeof(int)) + 255) & ~(size_t)255;
    size_t st_bytes = (((size_t)n * sizeof(f2)) + 255) & ~(size_t)255;
    size_t tb_bytes = (size_t)n * DIM * sizeof(unsigned short);
    int* rp1 = (int*)ws;
    int* rp2 = (int*)(ws + rp_bytes);
    f2*  ST  = (f2*)(ws + 2 * rp_bytes);
    unsigned short* T0 = (unsigned short*)(ws + 2 * rp_bytes + st_bytes);
    unsigned short* E1 = (unsigned short*)((char*)T0 + tb_bytes);
    unsigned short* E2 = (unsigned short*)((char*)E1 + tb_bytes);
    unsigned short* E3 = (unsigned short*)((char*)E2 + tb_bytes);

    const int tb = 256;
    build_row_ptr_kernel<<<(n + 1 + tb - 1) / tb, tb, 0, stream>>>(rows,  nnz,  n, rp1);
    build_row_ptr_kernel<<<(n + 1 + tb - 1) / tb, tb, 0, stream>>>(rows2, nnz2, n, rp2);

    const int n8 = n * DIM / 8;
    cvt_bf16_kernel<<<(n8 + tb - 1) / tb, tb, 0, stream>>>(emb, (unsigned int*)T0, n8);

    const int grid = (n + 3) / 4;  // 4 waves (rows) per 256-thread block
    // e1 = A1 @ t0 ; y-stats
    layer_kernel<0><<<grid, tb, 0, stream>>>(emb, T0, T0, vals, cols, rp1, n,
                                             E1, T0, T0, ST, out);
    // e2 from e1
    layer_kernel<1><<<grid, tb, 0, stream>>>(emb, T0, E1, vals2, cols2, rp2, n,
                                             E2, T0, T0, ST, out);
    // e3 from e2
    layer_kernel<1><<<grid, tb, 0, stream>>>(emb, T0, E2, vals2, cols2, rp2, n,
                                             E3, T0, T0, ST, out);
    // final: e4 from e3, fused mean -> out
    layer_kernel<2><<<grid, tb, 0, stream>>>(emb, T0, E3, vals2, cols2, rp2, n,
                                             E3, E1, E2, ST, out);
}

// Round 6
// 496.346 us; speedup vs baseline: 4.1797x; 1.3171x over previous
//
#include <hip/hip_runtime.h>

#define DIM 64

typedef __attribute__((ext_vector_type(4))) float f4;
typedef __attribute__((ext_vector_type(2))) float f2;
typedef __attribute__((ext_vector_type(4))) unsigned int u4;
typedef __attribute__((ext_vector_type(2))) unsigned int u2;

#define SEL_LO 0x01000504u   // [ga.lo16 in lo : gb.lo16 in hi]
#define SEL_HI 0x03020706u   // [ga.hi16 in lo : gb.hi16 in hi]
#define ONE2   0x3f803f80u   // bf16 pair (1.0, 1.0)

// ---- bf16 helpers ----
__device__ __forceinline__ float bflo(unsigned u) { return __uint_as_float(u << 16); }
__device__ __forceinline__ float bfhi(unsigned u) { return __uint_as_float(u & 0xffff0000u); }
__device__ __forceinline__ unsigned bfr(float f) {
    unsigned u = __float_as_uint(f);
    return (u + 0x7fffu + ((u >> 16) & 1u)) >> 16;
}
__device__ __forceinline__ unsigned packbf(float e, float o) { return bfr(e) | (bfr(o) << 16); }
// packed f32->bf16 pair (RNE), lo = first arg
__device__ __forceinline__ unsigned cvtpk(float lo, float hi) {
    unsigned r;
    asm("v_cvt_pk_bf16_f32 %0, %1, %2" : "=v"(r) : "v"(lo), "v"(hi));
    return r;
}
// D = a.lo*b.lo + a.hi*b.hi + c   (bf16 pairs, f32 accumulate)
__device__ __forceinline__ float dot2bf(unsigned a, unsigned b, float c) {
    float d;
    asm("v_dot2_f32_bf16 %0, %1, %2, %3" : "=v"(d) : "v"(a), "v"(b), "v"(c));
    return d;
}
// sum within each 8-lane group (xor masks 1,2,4 stay inside the group)
__device__ __forceinline__ float gsum8(float v) {
    v += __shfl_xor(v, 1, 64);
    v += __shfl_xor(v, 2, 64);
    v += __shfl_xor(v, 4, 64);
    return v;
}

// row_ptr[r] = lower_bound(rows, r) over sorted rows.
__global__ void build_row_ptr_kernel(const int* __restrict__ rows, int nnz,
                                     int n, int* __restrict__ row_ptr) {
    int r = blockIdx.x * blockDim.x + threadIdx.x;
    if (r > n) return;
    int lo = 0, hi = nnz;
    while (lo < hi) {
        int mid = (lo + hi) >> 1;
        if (rows[mid] < r) lo = mid + 1; else hi = mid;
    }
    row_ptr[r] = lo;
}

// f32 -> packed bf16 table, 8 elems per thread.
__global__ void cvt_bf16_kernel(const float* __restrict__ in,
                                unsigned int* __restrict__ out, int n8) {
    int i = blockIdx.x * blockDim.x + threadIdx.x;
    if (i >= n8) return;
    const f4* p = (const f4*)in + 2 * (size_t)i;
    f4 a = p[0], b = p[1];
    u4 o;
    o.x = packbf(a.x, a.y); o.y = packbf(a.z, a.w);
    o.z = packbf(b.x, b.y); o.w = packbf(b.z, b.w);
    ((u4*)out)[i] = o;
}

// One ROW per 8-lane group (8 rows per wave). Lane j of group g owns dims
// 8j..8j+7 of row (8*wave+g) and accumulates them in-register over all nnz
// of its row -- no cross-group reduction needed. Gathers still coalesce
// 8 rows x 128B = 1KB per instruction.
//
// MODE 0: e1 = A1 @ t0 -> enew; per-row y-stats (my, sqrt(vy)) from t0.
// MODE 1: prop = A2@eprev; b = pearson(eprev,t0); en = b*prop+(1-b)*t0 -> enew
// MODE 2: as MODE1 with y0 = emb(f32); out = (emb + e1 + e2 + eprev + en)/5
template <int MODE>
__global__ __launch_bounds__(256) void layer_kernel(
    const float* __restrict__ emb,
    const unsigned short* __restrict__ t0,
    const unsigned short* __restrict__ eprev,
    const float* __restrict__ vals, const int* __restrict__ cols,
    const int* __restrict__ rp, int n,
    unsigned short* __restrict__ enew,
    const unsigned short* __restrict__ e1t,
    const unsigned short* __restrict__ e2t,
    f2* __restrict__ stats,
    float* __restrict__ out)
{
    const int tid  = threadIdx.x;
    const int lane = tid & 63;
    const int j    = lane & 7;                       // dim chunk within group
    const int wave = blockIdx.x * (blockDim.x >> 6) + (tid >> 6);
    const int rowg = wave * 8 + (lane >> 3);         // this group's row
    const int rg   = rowg < n ? rowg : n - 1;        // clamped for loads

    const int start = rp[rg];
    const int end   = rp[rg + 1];
    const int len   = (rowg < n) ? (end - start) : 0;
    const int b0    = start & ~1;                    // 8B-aligned col/val base
    const int doff  = b0 - start;                    // 0 or -1

    // wave-wide max row length -> uniform step count (masked slots: val=0)
    int ml = len;
    ml = max(ml, __shfl_xor(ml, 8, 64));
    ml = max(ml, __shfl_xor(ml, 16, 64));
    ml = max(ml, __shfl_xor(ml, 32, 64));
    const int steps = (ml + 4) >> 2;                 // 4 nnz per step

    const char* tb8 = (const char*)eprev;            // gather table (t0 for MODE0 via launch arg)
    const unsigned joff = (unsigned)(j << 4);

    float acc[8] = {0.f, 0.f, 0.f, 0.f, 0.f, 0.f, 0.f, 0.f};

    for (int s = 0; s < steps; ++s) {
        const int k = b0 + (s << 2);
        u2 c01 = *(const u2*)(cols + k);             // 8B aligned (k even)
        u2 c23 = *(const u2*)(cols + k + 2);
        f2 v01 = *(const f2*)(vals + k);
        f2 v23 = *(const f2*)(vals + k + 2);
        const int rel = (s << 2) + doff;             // slot index rel. to start
        bool ok0 = (unsigned)(rel)     < (unsigned)len;
        bool ok1 = (unsigned)(rel + 1) < (unsigned)len;
        bool ok2 = (unsigned)(rel + 2) < (unsigned)len;
        bool ok3 = (unsigned)(rel + 3) < (unsigned)len;
        unsigned cc0 = ok0 ? (unsigned)c01.x : 0u;   // clamp col -> row 0 (L1 hit)
        unsigned cc1 = ok1 ? (unsigned)c01.y : 0u;
        unsigned cc2 = ok2 ? (unsigned)c23.x : 0u;
        unsigned cc3 = ok3 ? (unsigned)c23.y : 0u;
        float w0 = ok0 ? v01.x : 0.f;
        float w1 = ok1 ? v01.y : 0.f;
        float w2 = ok2 ? v23.x : 0.f;
        float w3 = ok3 ? v23.y : 0.f;
        unsigned vp01 = cvtpk(w0, w1);
        unsigned vp23 = cvtpk(w2, w3);
        u4 g0 = *(const u4*)(tb8 + ((cc0 << 7) + joff));
        u4 g1 = *(const u4*)(tb8 + ((cc1 << 7) + joff));
        u4 g2 = *(const u4*)(tb8 + ((cc2 << 7) + joff));
        u4 g3 = *(const u4*)(tb8 + ((cc3 << 7) + joff));
        acc[0] = dot2bf(__builtin_amdgcn_perm(g0.x, g1.x, SEL_LO), vp01, acc[0]);
        acc[1] = dot2bf(__builtin_amdgcn_perm(g0.x, g1.x, SEL_HI), vp01, acc[1]);
        acc[2] = dot2bf(__builtin_amdgcn_perm(g0.y, g1.y, SEL_LO), vp01, acc[2]);
        acc[3] = dot2bf(__builtin_amdgcn_perm(g0.y, g1.y, SEL_HI), vp01, acc[3]);
        acc[4] = dot2bf(__builtin_amdgcn_perm(g0.z, g1.z, SEL_LO), vp01, acc[4]);
        acc[5] = dot2bf(__builtin_amdgcn_perm(g0.z, g1.z, SEL_HI), vp01, acc[5]);
        acc[6] = dot2bf(__builtin_amdgcn_perm(g0.w, g1.w, SEL_LO), vp01, acc[6]);
        acc[7] = dot2bf(__builtin_amdgcn_perm(g0.w, g1.w, SEL_HI), vp01, acc[7]);
        acc[0] = dot2bf(__builtin_amdgcn_perm(g2.x, g3.x, SEL_LO), vp23, acc[0]);
        acc[1] = dot2bf(__builtin_amdgcn_perm(g2.x, g3.x, SEL_HI), vp23, acc[1]);
        acc[2] = dot2bf(__builtin_amdgcn_perm(g2.y, g3.y, SEL_LO), vp23, acc[2]);
        acc[3] = dot2bf(__builtin_amdgcn_perm(g2.y, g3.y, SEL_HI), vp23, acc[3]);
        acc[4] = dot2bf(__builtin_amdgcn_perm(g2.z, g3.z, SEL_LO), vp23, acc[4]);
        acc[5] = dot2bf(__builtin_amdgcn_perm(g2.z, g3.z, SEL_HI), vp23, acc[5]);
        acc[6] = dot2bf(__builtin_amdgcn_perm(g2.w, g3.w, SEL_LO), vp23, acc[6]);
        acc[7] = dot2bf(__builtin_amdgcn_perm(g2.w, g3.w, SEL_HI), vp23, acc[7]);
    }

    const size_t ro = (size_t)rg << 6;  // row offset in elements

    if (MODE == 0) {
        // y-stats of t0 row (loop-invariant across layers)
        u4 yr = *((const u4*)(t0 + ro) + j);
        float sy  = dot2bf(yr.x, ONE2,
                    dot2bf(yr.y, ONE2, dot2bf(yr.z, ONE2, dot2bf(yr.w, ONE2, 0.f))));
        float syy = dot2bf(yr.x, yr.x,
                    dot2bf(yr.y, yr.y, dot2bf(yr.z, yr.z, dot2bf(yr.w, yr.w, 0.f))));
        sy = gsum8(sy); syy = gsum8(syy);
        float my  = sy * (1.f / 64.f);
        float vy  = syy - sy * my;
        float svy = sqrtf(fmaxf(vy, 0.f));
        if (rowg < n) {
            if (j == 0) { f2 st; st.x = my; st.y = svy; stats[rowg] = st; }
            u4 o;
            o.x = cvtpk(acc[0], acc[1]); o.y = cvtpk(acc[2], acc[3]);
            o.z = cvtpk(acc[4], acc[5]); o.w = cvtpk(acc[6], acc[7]);
            *((u4*)(enew + ro) + j) = o;
        }
        return;
    }

    // Pearson(eprev_row, t0_row) with precomputed y-stats.
    u4 xr = *((const u4*)(eprev + ro) + j);
    u4 yr = *((const u4*)(t0 + ro) + j);
    float sx  = dot2bf(xr.x, ONE2,
                dot2bf(xr.y, ONE2, dot2bf(xr.z, ONE2, dot2bf(xr.w, ONE2, 0.f))));
    float sxx = dot2bf(xr.x, xr.x,
                dot2bf(xr.y, xr.y, dot2bf(xr.z, xr.z, dot2bf(xr.w, xr.w, 0.f))));
    float sxy = dot2bf(xr.x, yr.x,
                dot2bf(xr.y, yr.y, dot2bf(xr.z, yr.z, dot2bf(xr.w, yr.w, 0.f))));
    sx = gsum8(sx); sxx = gsum8(sxx); sxy = gsum8(sxy);

    f2 st = stats[rg];
    float mx  = sx * (1.f / 64.f);
    float num = sxy - sx * st.x;          // sxy - 64*mx*my
    float vx  = sxx - sx * mx;            // sxx - 64*mx*mx
    float den = sqrtf(fmaxf(vx, 0.f)) * st.y;
    den = fmaxf(den, 1e-7f);
    float b  = num / den;
    float ob = 1.f - b;

    if (MODE == 1) {
        float y0[8] = { bflo(yr.x), bfhi(yr.x), bflo(yr.y), bfhi(yr.y),
                        bflo(yr.z), bfhi(yr.z), bflo(yr.w), bfhi(yr.w) };
        if (rowg < n) {
            u4 o;
            o.x = cvtpk(b * acc[0] + ob * y0[0], b * acc[1] + ob * y0[1]);
            o.y = cvtpk(b * acc[2] + ob * y0[2], b * acc[3] + ob * y0[3]);
            o.z = cvtpk(b * acc[4] + ob * y0[4], b * acc[5] + ob * y0[5]);
            o.w = cvtpk(b * acc[6] + ob * y0[6], b * acc[7] + ob * y0[7]);
            *((u4*)(enew + ro) + j) = o;
        }
    } else {
        const f4* ep = (const f4*)(emb + ro) + 2 * j;
        f4 ea = ep[0], eb = ep[1];
        float y0[8] = { ea.x, ea.y, ea.z, ea.w, eb.x, eb.y, eb.z, eb.w };
        float xp[8] = { bflo(xr.x), bfhi(xr.x), bflo(xr.y), bfhi(xr.y),
                        bflo(xr.z), bfhi(xr.z), bflo(xr.w), bfhi(xr.w) };
        u4 r1 = *((const u4*)(e1t + ro) + j);
        u4 r2 = *((const u4*)(e2t + ro) + j);
        float s[8];
        s[0] = y0[0] + bflo(r1.x) + bflo(r2.x) + xp[0] + (b * acc[0] + ob * y0[0]);
        s[1] = y0[1] + bfhi(r1.x) + bfhi(r2.x) + xp[1] + (b * acc[1] + ob * y0[1]);
        s[2] = y0[2] + bflo(r1.y) + bflo(r2.y) + xp[2] + (b * acc[2] + ob * y0[2]);
        s[3] = y0[3] + bfhi(r1.y) + bfhi(r2.y) + xp[3] + (b * acc[3] + ob * y0[3]);
        s[4] = y0[4] + bflo(r1.z) + bflo(r2.z) + xp[4] + (b * acc[4] + ob * y0[4]);
        s[5] = y0[5] + bfhi(r1.z) + bfhi(r2.z) + xp[5] + (b * acc[5] + ob * y0[5]);
        s[6] = y0[6] + bflo(r1.w) + bflo(r2.w) + xp[6] + (b * acc[6] + ob * y0[6]);
        s[7] = y0[7] + bfhi(r1.w) + bfhi(r2.w) + xp[7] + (b * acc[7] + ob * y0[7]);
        if (rowg < n) {
            f4 o0 = { s[0] * 0.2f, s[1] * 0.2f, s[2] * 0.2f, s[3] * 0.2f };
            f4 o1 = { s[4] * 0.2f, s[5] * 0.2f, s[6] * 0.2f, s[7] * 0.2f };
            f4* op = (f4*)(out + ro) + 2 * j;
            op[0] = o0; op[1] = o1;
        }
    }
}

extern "C" void kernel_launch(void* const* d_in, const int* in_sizes, int n_in,
                              void* d_out, int out_size, void* d_ws, size_t ws_size,
                              hipStream_t stream) {
    const float* emb   = (const float*)d_in[0];
    const float* vals  = (const float*)d_in[1];
    const float* vals2 = (const float*)d_in[2];
    const int*   rows  = (const int*)d_in[3];
    const int*   cols  = (const int*)d_in[4];
    const int*   rows2 = (const int*)d_in[5];
    const int*   cols2 = (const int*)d_in[6];
    // n_layers = 3 (fixed for this problem)

    const int n    = in_sizes[0] / DIM;   // 300000
    const int nnz  = in_sizes[1];         // 4800000
    const int nnz2 = in_sizes[2];

    float* out = (float*)d_out;

    // ws: rp1 | rp2 | ST | T0 | E1 | E2 | E3  (~158.4 MB)
    char*  ws       = (char*)d_ws;
    size_t rp_bytes = (((size_t)(n + 1) * sizeof(int)) + 255) & ~(size_t)255;
    size_t st_bytes = (((size_t)n * sizeof(f2)) + 255) & ~(size_t)255;
    size_t tb_bytes = (size_t)n * DIM * sizeof(unsigned short);
    int* rp1 = (int*)ws;
    int* rp2 = (int*)(ws + rp_bytes);
    f2*  ST  = (f2*)(ws + 2 * rp_bytes);
    unsigned short* T0 = (unsigned short*)(ws + 2 * rp_bytes + st_bytes);
    unsigned short* E1 = (unsigned short*)((char*)T0 + tb_bytes);
    unsigned short* E2 = (unsigned short*)((char*)E1 + tb_bytes);
    unsigned short* E3 = (unsigned short*)((char*)E2 + tb_bytes);

    const int tb = 256;
    build_row_ptr_kernel<<<(n + 1 + tb - 1) / tb, tb, 0, stream>>>(rows,  nnz,  n, rp1);
    build_row_ptr_kernel<<<(n + 1 + tb - 1) / tb, tb, 0, stream>>>(rows2, nnz2, n, rp2);

    const int n8 = n * DIM / 8;
    cvt_bf16_kernel<<<(n8 + tb - 1) / tb, tb, 0, stream>>>(emb, (unsigned int*)T0, n8);

    const int waves = (n + 7) / 8;            // 8 rows per wave
    const int grid  = (waves + 3) / 4;        // 4 waves per 256-thread block
    // e1 = A1 @ t0 ; y-stats
    layer_kernel<0><<<grid, tb, 0, stream>>>(emb, T0, T0, vals, cols, rp1, n,
                                             E1, T0, T0, ST, out);
    // e2 from e1
    layer_kernel<1><<<grid, tb, 0, stream>>>(emb, T0, E1, vals2, cols2, rp2, n,
                                             E2, T0, T0, ST, out);
    // e3 from e2
    layer_kernel<1><<<grid, tb, 0, stream>>>(emb, T0, E2, vals2, cols2, rp2, n,
                                             E3, T0, T0, ST, out);
    // final: e4 from e3, fused mean -> out
    layer_kernel<2><<<grid, tb, 0, stream>>>(emb, T0, E3, vals2, cols2, rp2, n,
                                             E3, E1, E2, ST, out);
}